// Round 9
// baseline (330.503 us; speedup 1.0000x reference)
//
#include <hip/hip_runtime.h>
#include <hip/hip_bf16.h>

typedef __hip_bfloat16 bf16;
typedef __attribute__((ext_vector_type(4))) float f32x4;
typedef __attribute__((ext_vector_type(8))) short s16x8;

#define N_TOK 4096   // B*S
#define Dm    512
#define Fm    2048
#define Em    8

__device__ __forceinline__ float bf2f(bf16 v) { return __bfloat162float(v); }
__device__ __forceinline__ bf16  f2bf(float f) { return __float2bfloat16(f); }

// async global->LDS, 16B per lane; LDS dest is wave-uniform base + lane*16
#define GL16(g, l)                                                              \
  __builtin_amdgcn_global_load_lds(                                             \
      (const __attribute__((address_space(1))) void*)(g),                       \
      (__attribute__((address_space(3))) void*)(l), 16, 0, 0)

// ---------------- fp32 -> bf16 flat convert ----------------------------------
__global__ void cvt_f32_bf16(const float* __restrict__ in, bf16* __restrict__ out, int n4) {
  int i = blockIdx.x * 256 + threadIdx.x;
  if (i >= n4) return;
  float4 v = reinterpret_cast<const float4*>(in)[i];
  bf16 tmp[4] = {f2bf(v.x), f2bf(v.y), f2bf(v.z), f2bf(v.w)};
  __builtin_memcpy(out + (size_t)i * 4, tmp, 8);
}

// ---------------- fp32 [R][C] -> bf16 [C][R] tiled transpose-convert ---------
__global__ void transpose_cvt(const float* __restrict__ in, bf16* __restrict__ out,
                              int R, int C, long inb, long outb) {
  in  += (long)blockIdx.z * inb;
  out += (long)blockIdx.z * outb;
  __shared__ float t[32][33];
  int tx = threadIdx.x & 31, ty = threadIdx.x >> 5;
  int c0 = blockIdx.x * 32, r0 = blockIdx.y * 32;
#pragma unroll
  for (int i = 0; i < 32; i += 8)
    t[ty + i][tx] = in[(long)(r0 + ty + i) * C + c0 + tx];
  __syncthreads();
#pragma unroll
  for (int i = 0; i < 32; i += 8)
    out[(long)(c0 + ty + i) * R + r0 + tx] = f2bf(t[tx][ty + i]);
}

// ======== 128x128 BK=64 bf16 GEMM: round-1 structure + swizzle + occupancy ===
// C = A @ Bt^T (+bias[, relu]).  A:[M][K] lda, Bt:[N][K] ldb, C row-major ldc.
// 4 waves (2x2), wave tile 64x64, BK=64, 32 KB static LDS, 2 barriers/K-iter.
// __launch_bounds__(256,4): target 4 blocks/CU (16 waves) for cross-block
// overlap of the barrier drain (m114 mechanism). Chunk-XOR swizzle
// (phys_slot = logical_slot ^ (row&7)) applied on BOTH sides: inverse on the
// global SOURCE of global_load_lds (LDS dest stays linear, rule #21) and on
// the ds_read address. row&7 == la&7 for all fragment rows (bases are
// multiples of 16), so reads spread 16 lanes over 8 slot groups -> 2-way max
// (free, m136). Swapped MFMA operands (verified r8): acc[m][n][r] lands at
// C[.. + m*16 + la][.. + n*16 + q*4 + r] -> packed 8B/16B stores.
template <bool RELU, bool OUT_BF16>
__global__ __launch_bounds__(256, 4) void gemm128(
    const bf16* __restrict__ A, const bf16* __restrict__ Bt, void* __restrict__ Cout,
    const float* __restrict__ bias, int K, int lda, int ldb, int ldc,
    long abs_, long bbs, long cbs, long biasbs, int gx, int gy,
    const int* __restrict__ eid, int eid_scale) {
  __shared__ bf16 As[128 * 64];
  __shared__ bf16 Bs[128 * 64];

  // XCD-aware bijective swizzle (gridDim.x % 8 == 0 by construction)
  int nwg = gridDim.x;
  int id  = blockIdx.x;
  int lid = (id & 7) * (nwg >> 3) + (id >> 3);
  int per = gx * gy;
  int e   = lid / per;
  int rem = lid - e * per;
  int bx  = rem % gx, by = rem / gx;
  int bm  = bx * 128, bn = by * 128;

  A    += (long)e * abs_;
  Bt   += (long)e * bbs;
  bias += (long)e * biasbs;
  long coff = (long)e * cbs;
  if (eid) A += (long)(*eid) * eid_scale;

  int tid = threadIdx.x, wv = tid >> 6, lane = tid & 63;
  int wm = wv >> 1, wn = wv & 1;

  const bf16* Ab = A + (long)bm * lda;
  const bf16* Bb = Bt + (long)bn * ldb;

  f32x4 acc[4][4] = {};
  int la = lane & 15, q = lane >> 4;
  int srow_lo = lane >> 3;  // staging row within 8-row group

  for (int k0 = 0; k0 < K; k0 += 64) {
    __syncthreads();  // previous compute done before overwrite
#pragma unroll
    for (int j = 0; j < 4; ++j) {
      int r = (wv * 4 + j) * 8 + srow_lo;
      int c = (lane & 7) ^ (r & 7);  // inverse-swizzled source chunk
      GL16(Ab + (long)r * lda + k0 + c * 8, As + (wv * 4 + j) * 512);
      GL16(Bb + (long)r * ldb + k0 + c * 8, Bs + (wv * 4 + j) * 512);
    }
    __syncthreads();  // drain (vmcnt 0): staged data visible

#pragma unroll
    for (int kk = 0; kk < 2; ++kk) {  // sequential kk keeps VGPR peak low
      int ps = (kk * 4 + q) ^ (la & 7);  // swizzled ds_read slot
      s16x8 af[4], bfr[4];
#pragma unroll
      for (int m = 0; m < 4; ++m)
        af[m] = *reinterpret_cast<const s16x8*>(As + (wm * 64 + m * 16 + la) * 64 + ps * 8);
#pragma unroll
      for (int n = 0; n < 4; ++n)
        bfr[n] = *reinterpret_cast<const s16x8*>(Bs + (wn * 64 + n * 16 + la) * 64 + ps * 8);
#pragma unroll
      for (int m = 0; m < 4; ++m)
#pragma unroll
        for (int n = 0; n < 4; ++n)
          acc[m][n] = __builtin_amdgcn_mfma_f32_16x16x32_bf16(bfr[n], af[m], acc[m][n], 0, 0, 0);
    }
  }

  // epilogue: acc[m][n][r] -> C[bm+wm*64+m*16+la][bn+wn*64+n*16+q*4+r]
#pragma unroll
  for (int m = 0; m < 4; ++m) {
    int gm = bm + wm * 64 + m * 16 + la;
#pragma unroll
    for (int n = 0; n < 4; ++n) {
      int gn = bn + wn * 64 + n * 16 + q * 4;
      float4 b4 = *reinterpret_cast<const float4*>(bias + gn);
      float v0 = acc[m][n][0] + b4.x, v1 = acc[m][n][1] + b4.y;
      float v2 = acc[m][n][2] + b4.z, v3 = acc[m][n][3] + b4.w;
      if (RELU) {
        v0 = fmaxf(v0, 0.f); v1 = fmaxf(v1, 0.f);
        v2 = fmaxf(v2, 0.f); v3 = fmaxf(v3, 0.f);
      }
      long idx = coff + (long)gm * ldc + gn;
      if (OUT_BF16) {
        bf16 tmp[4] = {f2bf(v0), f2bf(v1), f2bf(v2), f2bf(v3)};
        __builtin_memcpy((bf16*)Cout + idx, tmp, 8);
      } else {
        float tmp[4] = {v0, v1, v2, v3};
        __builtin_memcpy((float*)Cout + idx, tmp, 16);
      }
    }
  }
}

// ---------------- 128x128 BK=32 bf16 GEMM (verbatim round-1; Q & out-proj) ---
template <bool RELU, bool OUT_BF16>
__global__ __launch_bounds__(256, 2) void gemm_bt(
    const bf16* __restrict__ A, const bf16* __restrict__ Bt, void* __restrict__ Cout,
    const float* __restrict__ bias, int M, int N, int K, int lda, int ldb, int ldc,
    long abs_, long bbs, long cbs, long biasbs, const int* __restrict__ eid,
    int eid_scale) {
  int e = blockIdx.z;
  A    += (long)e * abs_;
  Bt   += (long)e * bbs;
  bias += (long)e * biasbs;
  long coff = (long)e * cbs;
  if (eid) A += (long)(*eid) * eid_scale;

  __shared__ bf16 As[128 * 32];
  __shared__ bf16 Bs[128 * 32];

  int tid = threadIdx.x;
  int wave = tid >> 6, lane = tid & 63;
  int wm = wave >> 1, wn = wave & 1;
  int bm = blockIdx.x * 128, bn = blockIdx.y * 128;

  int srow  = lane >> 2;
  int skoff = (lane & 3) * 8;

  f32x4 acc[4][4] = {};

  const bf16* Abase = A + (long)bm * lda;
  const bf16* Bbase = Bt + (long)bn * ldb;

  for (int k0 = 0; k0 < K; k0 += 32) {
    __syncthreads();
#pragma unroll
    for (int i = 0; i < 2; i++) {
      int r = wave * 32 + i * 16 + srow;
      GL16(Abase + (long)r * lda + k0 + skoff, As + (wave * 32 + i * 16) * 32);
      GL16(Bbase + (long)r * ldb + k0 + skoff, Bs + (wave * 32 + i * 16) * 32);
    }
    __syncthreads();

    s16x8 af[4], bfr[4];
#pragma unroll
    for (int m = 0; m < 4; m++)
      af[m] = *reinterpret_cast<const s16x8*>(As + (wm * 64 + m * 16 + (lane & 15)) * 32 +
                                              (lane >> 4) * 8);
#pragma unroll
    for (int n = 0; n < 4; n++)
      bfr[n] = *reinterpret_cast<const s16x8*>(Bs + (wn * 64 + n * 16 + (lane & 15)) * 32 +
                                               (lane >> 4) * 8);
#pragma unroll
    for (int m = 0; m < 4; m++)
#pragma unroll
      for (int n = 0; n < 4; n++)
        acc[m][n] = __builtin_amdgcn_mfma_f32_16x16x32_bf16(af[m], bfr[n], acc[m][n], 0, 0, 0);
  }

  int cr = (lane >> 4) * 4, cc = lane & 15;
#pragma unroll
  for (int m = 0; m < 4; m++) {
#pragma unroll
    for (int n = 0; n < 4; n++) {
      int col  = bn + wn * 64 + n * 16 + cc;
      float bv = bias ? bias[col] : 0.0f;
#pragma unroll
      for (int r = 0; r < 4; r++) {
        int row = bm + wm * 64 + m * 16 + cr + r;
        float v = acc[m][n][r] + bv;
        if (RELU) v = fmaxf(v, 0.0f);
        long idx = coff + (long)row * ldc + col;
        if (OUT_BF16)
          ((bf16*)Cout)[idx] = f2bf(v);
        else
          ((float*)Cout)[idx] = v;
      }
    }
  }
}

// ---------------- attention over the expert axis (E=8, H=8, HD=64) ----------
__global__ __launch_bounds__(256) void attn_kernel(const float* __restrict__ q,
                                                   const bf16* __restrict__ kv,
                                                   bf16* __restrict__ ctx,
                                                   const int* __restrict__ eid) {
  int wave = threadIdx.x >> 6, lane = threadIdx.x & 63;
  int n = blockIdx.x * 4 + wave;
  int h = lane >> 3, f = lane & 7;
  int e3 = *eid;
  const bf16* kvn = kv + (long)n * Em * (2 * Dm);
  const float* qh = q + (long)n * Dm + h * 64;
  const bf16* kf = kvn + f * (2 * Dm) + h * 64;
  float s = 0.f;
#pragma unroll
  for (int j = 0; j < 64; j++) s += qh[j] * bf2f(kf[j]);
  s *= 0.125f;
  s += (f <= e3) ? 1.0f : 0.0f;  // torch-faithful ADDITIVE float tril mask
  float mx = s;
#pragma unroll
  for (int d = 1; d < 8; d <<= 1) mx = fmaxf(mx, __shfl_xor(mx, d));
  float ex = expf(s - mx);
  float sm = ex;
#pragma unroll
  for (int d = 1; d < 8; d <<= 1) sm += __shfl_xor(sm, d);
  float at = ex / sm;
  int g = f;
  float acc[8] = {0, 0, 0, 0, 0, 0, 0, 0};
#pragma unroll
  for (int f2 = 0; f2 < 8; f2++) {
    float a = __shfl(at, (h << 3) | f2);
    const bf16* vf = kvn + f2 * (2 * Dm) + Dm + h * 64 + g * 8;
#pragma unroll
    for (int j = 0; j < 8; j++) acc[j] += a * bf2f(vf[j]);
  }
  bf16 tmp[8];
#pragma unroll
  for (int j = 0; j < 8; j++) tmp[j] = f2bf(acc[j]);
  __builtin_memcpy(ctx + (long)n * Dm + h * 64 + g * 8, tmp, 16);
}

extern "C" void kernel_launch(void* const* d_in, const int* in_sizes, int n_in,
                              void* d_out, int out_size, void* d_ws, size_t ws_size,
                              hipStream_t stream) {
  const float* x  = (const float*)d_in[0];
  const float* W1 = (const float*)d_in[1];
  const float* b1 = (const float*)d_in[2];
  const float* W2 = (const float*)d_in[3];
  const float* b2 = (const float*)d_in[4];
  const float* Wq = (const float*)d_in[5];
  const float* bq = (const float*)d_in[6];
  const float* Wk = (const float*)d_in[7];
  const float* bk = (const float*)d_in[8];
  const float* Wv = (const float*)d_in[9];
  const float* bv = (const float*)d_in[10];
  const float* Wo = (const float*)d_in[11];
  const float* bo = (const float*)d_in[12];
  const int* eid  = (const int*)d_in[13];

  char* w = (char*)d_ws;
  auto alloc = [&](size_t bytes) {
    char* p = w;
    w += (bytes + 255) & ~(size_t)255;
    return p;
  };
  bf16* xb   = (bf16*)alloc((size_t)N_TOK * Dm * 2);
  bf16* W1t  = (bf16*)alloc((size_t)Em * Fm * Dm * 2);
  bf16* W2t  = (bf16*)alloc((size_t)Em * Dm * Fm * 2);
  bf16* qw   = (bf16*)alloc((size_t)Dm * Dm * 2);
  bf16* kvw  = (bf16*)alloc((size_t)2 * Dm * Dm * 2);
  bf16* ow   = (bf16*)alloc((size_t)Dm * Dm * 2);
  float* bkv = (float*)alloc((size_t)2 * Dm * 4);
  bf16* hid  = (bf16*)alloc((size_t)Em * N_TOK * Fm * 2);   // 128 MB [e][n][f]
  bf16* eo   = (bf16*)alloc((size_t)N_TOK * Em * Dm * 2);   // [n][e][d]
  bf16* kv   = (bf16*)hid;                                  // alias: [n*E+e][2D]
  float* qb  = (float*)(hid + (size_t)N_TOK * Em * 2 * Dm);
  bf16* ctxb = (bf16*)(qb + (size_t)N_TOK * Dm);

  // ---- converts / transposes ----
  cvt_f32_bf16<<<(N_TOK * Dm / 4 + 255) / 256, 256, 0, stream>>>(x, xb, N_TOK * Dm / 4);
  transpose_cvt<<<dim3(Fm / 32, Dm / 32, Em), 256, 0, stream>>>(
      W1, W1t, Dm, Fm, (long)Dm * Fm, (long)Fm * Dm);
  transpose_cvt<<<dim3(Dm / 32, Fm / 32, Em), 256, 0, stream>>>(
      W2, W2t, Fm, Dm, (long)Fm * Dm, (long)Dm * Fm);
  int nw4 = Dm * Dm / 4;
  cvt_f32_bf16<<<(nw4 + 255) / 256, 256, 0, stream>>>(Wq, qw, nw4);
  cvt_f32_bf16<<<(nw4 + 255) / 256, 256, 0, stream>>>(Wk, kvw, nw4);
  cvt_f32_bf16<<<(nw4 + 255) / 256, 256, 0, stream>>>(Wv, kvw + (size_t)Dm * Dm, nw4);
  cvt_f32_bf16<<<(nw4 + 255) / 256, 256, 0, stream>>>(Wo, ow, nw4);
  hipMemcpyAsync(bkv, bk, Dm * sizeof(float), hipMemcpyDeviceToDevice, stream);
  hipMemcpyAsync(bkv + Dm, bv, Dm * sizeof(float), hipMemcpyDeviceToDevice, stream);

  // ---- FFN stage 1: hid[e] = relu(x @ W1[e] + b1[e])  M=4096 N=2048 K=512
  gemm128<true, true><<<32 * 16 * Em, 256, 0, stream>>>(
      xb, W1t, hid, b1, Dm, Dm, Dm, Fm,
      0L, (long)Fm * Dm, (long)N_TOK * Fm, (long)Fm, 32, 16, nullptr, 0);
  // ---- FFN stage 2: eo[n][e][:] = hid[e] @ W2[e] + b2[e]  M=4096 N=512 K=2048
  gemm128<false, true><<<32 * 4 * Em, 256, 0, stream>>>(
      hid, W2t, eo, b2, Fm, Fm, Fm, Em * Dm,
      (long)N_TOK * Fm, (long)Dm * Fm, (long)Dm, (long)Dm, 32, 4, nullptr, 0);
  // ---- K|V for all expert rows: M=32768 N=1024 K=512
  gemm128<false, true><<<256 * 8, 256, 0, stream>>>(
      eo, kvw, kv, bkv, Dm, Dm, Dm, 2 * Dm,
      0L, 0L, 0L, 0L, 256, 8, nullptr, 0);
  // ---- Q only for expert row e_id (small: keep BK=32 kernel)
  gemm_bt<false, false><<<dim3(N_TOK / 128, Dm / 128, 1), 256, 0, stream>>>(
      eo, qw, qb, bq, N_TOK, Dm, Dm, Em * Dm, Dm, Dm,
      0L, 0L, 0L, 0L, eid, Dm);
  // ---- attention over experts ----
  attn_kernel<<<N_TOK / 4, 256, 0, stream>>>(qb, kv, ctxb, eid);
  // ---- out projection -> d_out (fp32) ----
  gemm_bt<false, false><<<dim3(N_TOK / 128, Dm / 128, 1), 256, 0, stream>>>(
      ctxb, ow, (float*)d_out, bo, N_TOK, Dm, Dm, Dm, Dm, Dm,
      0L, 0L, 0L, 0L, nullptr, 0);
}

// Round 10
// 310.496 us; speedup vs baseline: 1.0644x; 1.0644x over previous
//
#include <hip/hip_runtime.h>
#include <hip/hip_bf16.h>

typedef __hip_bfloat16 bf16;
typedef __attribute__((ext_vector_type(4))) float f32x4;
typedef __attribute__((ext_vector_type(8))) short s16x8;

#define N_TOK 4096   // B*S
#define Dm    512
#define Fm    2048
#define Em    8

__device__ __forceinline__ float bf2f(bf16 v) { return __bfloat162float(v); }
__device__ __forceinline__ bf16  f2bf(float f) { return __float2bfloat16(f); }

// async global->LDS, 16B per lane; LDS dest is wave-uniform base + lane*16
#define GL16(g, l)                                                              \
  __builtin_amdgcn_global_load_lds(                                             \
      (const __attribute__((address_space(1))) void*)(g),                       \
      (__attribute__((address_space(3))) void*)(l), 16, 0, 0)

// ---------------- fp32 -> bf16 flat convert ----------------------------------
__global__ void cvt_f32_bf16(const float* __restrict__ in, bf16* __restrict__ out, int n4) {
  int i = blockIdx.x * 256 + threadIdx.x;
  if (i >= n4) return;
  float4 v = reinterpret_cast<const float4*>(in)[i];
  bf16 tmp[4] = {f2bf(v.x), f2bf(v.y), f2bf(v.z), f2bf(v.w)};
  __builtin_memcpy(out + (size_t)i * 4, tmp, 8);
}

// ---------------- fp32 [R][C] -> bf16 [C][R] tiled transpose-convert ---------
__global__ void transpose_cvt(const float* __restrict__ in, bf16* __restrict__ out,
                              int R, int C, long inb, long outb) {
  in  += (long)blockIdx.z * inb;
  out += (long)blockIdx.z * outb;
  __shared__ float t[32][33];
  int tx = threadIdx.x & 31, ty = threadIdx.x >> 5;
  int c0 = blockIdx.x * 32, r0 = blockIdx.y * 32;
#pragma unroll
  for (int i = 0; i < 32; i += 8)
    t[ty + i][tx] = in[(long)(r0 + ty + i) * C + c0 + tx];
  __syncthreads();
#pragma unroll
  for (int i = 0; i < 32; i += 8)
    out[(long)(c0 + ty + i) * R + r0 + tx] = f2bf(t[tx][ty + i]);
}

// ======== 128x128 BK=64 bf16 GEMM, natural 2D grid (r10: NO XCD remap) =======
// C = A @ Bt^T (+bias[, relu]).  A:[M][K] lda, Bt:[N][K] ldb, C row-major ldc.
// grid = (M/128, N/128, batch) — natural x-fastest dispatch keeps per-XCD L2
// working sets small (r9's per-expert XCD remap built a 6MB/XCD set -> thrash,
// FETCH 2x). 4 waves (2x2), BK=64, 32 KB LDS, 2 barriers/K-iter.
// Chunk-XOR swizzle both sides (rule #21): inverse on global SOURCE of
// global_load_lds (LDS dest linear), same XOR on ds_read -> 0 bank conflicts
// (verified r9). Swapped MFMA operands: acc[m][n][r] ->
// C[..+m*16+la][..+n*16+q*4+r] -> packed 8B/16B stores (verified r8/r9).
template <bool RELU, bool OUT_BF16>
__global__ __launch_bounds__(256, 4) void gemm128(
    const bf16* __restrict__ A, const bf16* __restrict__ Bt, void* __restrict__ Cout,
    const float* __restrict__ bias, int K, int lda, int ldb, int ldc,
    long abs_, long bbs, long cbs, long biasbs,
    const int* __restrict__ eid, int eid_scale) {
  __shared__ bf16 As[128 * 64];
  __shared__ bf16 Bs[128 * 64];

  int e  = blockIdx.z;
  int bm = blockIdx.x * 128, bn = blockIdx.y * 128;

  A    += (long)e * abs_;
  Bt   += (long)e * bbs;
  bias += (long)e * biasbs;
  long coff = (long)e * cbs;
  if (eid) A += (long)(*eid) * eid_scale;

  int tid = threadIdx.x, wv = tid >> 6, lane = tid & 63;
  int wm = wv >> 1, wn = wv & 1;

  const bf16* Ab = A + (long)bm * lda;
  const bf16* Bb = Bt + (long)bn * ldb;

  f32x4 acc[4][4] = {};
  int la = lane & 15, q = lane >> 4;
  int srow_lo = lane >> 3;  // staging row within 8-row group

  for (int k0 = 0; k0 < K; k0 += 64) {
    __syncthreads();  // previous compute done before overwrite
#pragma unroll
    for (int j = 0; j < 4; ++j) {
      int r = (wv * 4 + j) * 8 + srow_lo;
      int c = (lane & 7) ^ (r & 7);  // inverse-swizzled source chunk
      GL16(Ab + (long)r * lda + k0 + c * 8, As + (wv * 4 + j) * 512);
      GL16(Bb + (long)r * ldb + k0 + c * 8, Bs + (wv * 4 + j) * 512);
    }
    __syncthreads();  // drain (vmcnt 0): staged data visible

#pragma unroll
    for (int kk = 0; kk < 2; ++kk) {  // sequential kk keeps VGPR peak low
      int ps = (kk * 4 + q) ^ (la & 7);  // swizzled ds_read slot
      s16x8 af[4], bfr[4];
#pragma unroll
      for (int m = 0; m < 4; ++m)
        af[m] = *reinterpret_cast<const s16x8*>(As + (wm * 64 + m * 16 + la) * 64 + ps * 8);
#pragma unroll
      for (int n = 0; n < 4; ++n)
        bfr[n] = *reinterpret_cast<const s16x8*>(Bs + (wn * 64 + n * 16 + la) * 64 + ps * 8);
#pragma unroll
      for (int m = 0; m < 4; ++m)
#pragma unroll
        for (int n = 0; n < 4; ++n)
          acc[m][n] = __builtin_amdgcn_mfma_f32_16x16x32_bf16(bfr[n], af[m], acc[m][n], 0, 0, 0);
    }
  }

  // epilogue: acc[m][n][r] -> C[bm+wm*64+m*16+la][bn+wn*64+n*16+q*4+r]
#pragma unroll
  for (int m = 0; m < 4; ++m) {
    int gm = bm + wm * 64 + m * 16 + la;
#pragma unroll
    for (int n = 0; n < 4; ++n) {
      int gn = bn + wn * 64 + n * 16 + q * 4;
      float4 b4 = *reinterpret_cast<const float4*>(bias + gn);
      float v0 = acc[m][n][0] + b4.x, v1 = acc[m][n][1] + b4.y;
      float v2 = acc[m][n][2] + b4.z, v3 = acc[m][n][3] + b4.w;
      if (RELU) {
        v0 = fmaxf(v0, 0.f); v1 = fmaxf(v1, 0.f);
        v2 = fmaxf(v2, 0.f); v3 = fmaxf(v3, 0.f);
      }
      long idx = coff + (long)gm * ldc + gn;
      if (OUT_BF16) {
        bf16 tmp[4] = {f2bf(v0), f2bf(v1), f2bf(v2), f2bf(v3)};
        __builtin_memcpy((bf16*)Cout + idx, tmp, 8);
      } else {
        float tmp[4] = {v0, v1, v2, v3};
        __builtin_memcpy((float*)Cout + idx, tmp, 16);
      }
    }
  }
}

// ---------------- 128x128 BK=32 bf16 GEMM (verbatim round-1; Q & out-proj) ---
template <bool RELU, bool OUT_BF16>
__global__ __launch_bounds__(256, 2) void gemm_bt(
    const bf16* __restrict__ A, const bf16* __restrict__ Bt, void* __restrict__ Cout,
    const float* __restrict__ bias, int M, int N, int K, int lda, int ldb, int ldc,
    long abs_, long bbs, long cbs, long biasbs, const int* __restrict__ eid,
    int eid_scale) {
  int e = blockIdx.z;
  A    += (long)e * abs_;
  Bt   += (long)e * bbs;
  bias += (long)e * biasbs;
  long coff = (long)e * cbs;
  if (eid) A += (long)(*eid) * eid_scale;

  __shared__ bf16 As[128 * 32];
  __shared__ bf16 Bs[128 * 32];

  int tid = threadIdx.x;
  int wave = tid >> 6, lane = tid & 63;
  int wm = wave >> 1, wn = wave & 1;
  int bm = blockIdx.x * 128, bn = blockIdx.y * 128;

  int srow  = lane >> 2;
  int skoff = (lane & 3) * 8;

  f32x4 acc[4][4] = {};

  const bf16* Abase = A + (long)bm * lda;
  const bf16* Bbase = Bt + (long)bn * ldb;

  for (int k0 = 0; k0 < K; k0 += 32) {
    __syncthreads();
#pragma unroll
    for (int i = 0; i < 2; i++) {
      int r = wave * 32 + i * 16 + srow;
      GL16(Abase + (long)r * lda + k0 + skoff, As + (wave * 32 + i * 16) * 32);
      GL16(Bbase + (long)r * ldb + k0 + skoff, Bs + (wave * 32 + i * 16) * 32);
    }
    __syncthreads();

    s16x8 af[4], bfr[4];
#pragma unroll
    for (int m = 0; m < 4; m++)
      af[m] = *reinterpret_cast<const s16x8*>(As + (wm * 64 + m * 16 + (lane & 15)) * 32 +
                                              (lane >> 4) * 8);
#pragma unroll
    for (int n = 0; n < 4; n++)
      bfr[n] = *reinterpret_cast<const s16x8*>(Bs + (wn * 64 + n * 16 + (lane & 15)) * 32 +
                                               (lane >> 4) * 8);
#pragma unroll
    for (int m = 0; m < 4; m++)
#pragma unroll
      for (int n = 0; n < 4; n++)
        acc[m][n] = __builtin_amdgcn_mfma_f32_16x16x32_bf16(af[m], bfr[n], acc[m][n], 0, 0, 0);
  }

  int cr = (lane >> 4) * 4, cc = lane & 15;
#pragma unroll
  for (int m = 0; m < 4; m++) {
#pragma unroll
    for (int n = 0; n < 4; n++) {
      int col  = bn + wn * 64 + n * 16 + cc;
      float bv = bias ? bias[col] : 0.0f;
#pragma unroll
      for (int r = 0; r < 4; r++) {
        int row = bm + wm * 64 + m * 16 + cr + r;
        float v = acc[m][n][r] + bv;
        if (RELU) v = fmaxf(v, 0.0f);
        long idx = coff + (long)row * ldc + col;
        if (OUT_BF16)
          ((bf16*)Cout)[idx] = f2bf(v);
        else
          ((float*)Cout)[idx] = v;
      }
    }
  }
}

// ---------------- attention over the expert axis (E=8, H=8, HD=64) ----------
__global__ __launch_bounds__(256) void attn_kernel(const float* __restrict__ q,
                                                   const bf16* __restrict__ kv,
                                                   bf16* __restrict__ ctx,
                                                   const int* __restrict__ eid) {
  int wave = threadIdx.x >> 6, lane = threadIdx.x & 63;
  int n = blockIdx.x * 4 + wave;
  int h = lane >> 3, f = lane & 7;
  int e3 = *eid;
  const bf16* kvn = kv + (long)n * Em * (2 * Dm);
  const float* qh = q + (long)n * Dm + h * 64;
  const bf16* kf = kvn + f * (2 * Dm) + h * 64;
  float s = 0.f;
#pragma unroll
  for (int j = 0; j < 64; j++) s += qh[j] * bf2f(kf[j]);
  s *= 0.125f;
  s += (f <= e3) ? 1.0f : 0.0f;  // torch-faithful ADDITIVE float tril mask
  float mx = s;
#pragma unroll
  for (int d = 1; d < 8; d <<= 1) mx = fmaxf(mx, __shfl_xor(mx, d));
  float ex = expf(s - mx);
  float sm = ex;
#pragma unroll
  for (int d = 1; d < 8; d <<= 1) sm += __shfl_xor(sm, d);
  float at = ex / sm;
  int g = f;
  float acc[8] = {0, 0, 0, 0, 0, 0, 0, 0};
#pragma unroll
  for (int f2 = 0; f2 < 8; f2++) {
    float a = __shfl(at, (h << 3) | f2);
    const bf16* vf = kvn + f2 * (2 * Dm) + Dm + h * 64 + g * 8;
#pragma unroll
    for (int j = 0; j < 8; j++) acc[j] += a * bf2f(vf[j]);
  }
  bf16 tmp[8];
#pragma unroll
  for (int j = 0; j < 8; j++) tmp[j] = f2bf(acc[j]);
  __builtin_memcpy(ctx + (long)n * Dm + h * 64 + g * 8, tmp, 16);
}

extern "C" void kernel_launch(void* const* d_in, const int* in_sizes, int n_in,
                              void* d_out, int out_size, void* d_ws, size_t ws_size,
                              hipStream_t stream) {
  const float* x  = (const float*)d_in[0];
  const float* W1 = (const float*)d_in[1];
  const float* b1 = (const float*)d_in[2];
  const float* W2 = (const float*)d_in[3];
  const float* b2 = (const float*)d_in[4];
  const float* Wq = (const float*)d_in[5];
  const float* bq = (const float*)d_in[6];
  const float* Wk = (const float*)d_in[7];
  const float* bk = (const float*)d_in[8];
  const float* Wv = (const float*)d_in[9];
  const float* bv = (const float*)d_in[10];
  const float* Wo = (const float*)d_in[11];
  const float* bo = (const float*)d_in[12];
  const int* eid  = (const int*)d_in[13];

  char* w = (char*)d_ws;
  auto alloc = [&](size_t bytes) {
    char* p = w;
    w += (bytes + 255) & ~(size_t)255;
    return p;
  };
  bf16* xb   = (bf16*)alloc((size_t)N_TOK * Dm * 2);
  bf16* W1t  = (bf16*)alloc((size_t)Em * Fm * Dm * 2);
  bf16* W2t  = (bf16*)alloc((size_t)Em * Dm * Fm * 2);
  bf16* qw   = (bf16*)alloc((size_t)Dm * Dm * 2);
  bf16* kvw  = (bf16*)alloc((size_t)2 * Dm * Dm * 2);
  bf16* ow   = (bf16*)alloc((size_t)Dm * Dm * 2);
  float* bkv = (float*)alloc((size_t)2 * Dm * 4);
  bf16* hid  = (bf16*)alloc((size_t)Em * N_TOK * Fm * 2);   // 128 MB [e][n][f]
  bf16* eo   = (bf16*)alloc((size_t)N_TOK * Em * Dm * 2);   // [n][e][d]
  bf16* kv   = (bf16*)hid;                                  // alias: [n*E+e][2D]
  float* qb  = (float*)(hid + (size_t)N_TOK * Em * 2 * Dm);
  bf16* ctxb = (bf16*)(qb + (size_t)N_TOK * Dm);

  // ---- converts / transposes ----
  cvt_f32_bf16<<<(N_TOK * Dm / 4 + 255) / 256, 256, 0, stream>>>(x, xb, N_TOK * Dm / 4);
  transpose_cvt<<<dim3(Fm / 32, Dm / 32, Em), 256, 0, stream>>>(
      W1, W1t, Dm, Fm, (long)Dm * Fm, (long)Fm * Dm);
  transpose_cvt<<<dim3(Dm / 32, Fm / 32, Em), 256, 0, stream>>>(
      W2, W2t, Fm, Dm, (long)Fm * Dm, (long)Dm * Fm);
  int nw4 = Dm * Dm / 4;
  cvt_f32_bf16<<<(nw4 + 255) / 256, 256, 0, stream>>>(Wq, qw, nw4);
  cvt_f32_bf16<<<(nw4 + 255) / 256, 256, 0, stream>>>(Wk, kvw, nw4);
  cvt_f32_bf16<<<(nw4 + 255) / 256, 256, 0, stream>>>(Wv, kvw + (size_t)Dm * Dm, nw4);
  cvt_f32_bf16<<<(nw4 + 255) / 256, 256, 0, stream>>>(Wo, ow, nw4);
  hipMemcpyAsync(bkv, bk, Dm * sizeof(float), hipMemcpyDeviceToDevice, stream);
  hipMemcpyAsync(bkv + Dm, bv, Dm * sizeof(float), hipMemcpyDeviceToDevice, stream);

  // ---- FFN stage 1: hid[e] = relu(x @ W1[e] + b1[e])  M=4096 N=2048 K=512
  gemm128<true, true><<<dim3(32, 16, Em), 256, 0, stream>>>(
      xb, W1t, hid, b1, Dm, Dm, Dm, Fm,
      0L, (long)Fm * Dm, (long)N_TOK * Fm, (long)Fm, nullptr, 0);
  // ---- FFN stage 2: eo[n][e][:] = hid[e] @ W2[e] + b2[e]  M=4096 N=512 K=2048
  gemm128<false, true><<<dim3(32, 4, Em), 256, 0, stream>>>(
      hid, W2t, eo, b2, Fm, Fm, Fm, Em * Dm,
      (long)N_TOK * Fm, (long)Dm * Fm, (long)Dm, (long)Dm, nullptr, 0);
  // ---- K|V for all expert rows: M=32768 N=1024 K=512
  gemm128<false, true><<<dim3(256, 8, 1), 256, 0, stream>>>(
      eo, kvw, kv, bkv, Dm, Dm, Dm, 2 * Dm,
      0L, 0L, 0L, 0L, nullptr, 0);
  // ---- Q only for expert row e_id (small: keep BK=32 kernel)
  gemm_bt<false, false><<<dim3(N_TOK / 128, Dm / 128, 1), 256, 0, stream>>>(
      eo, qw, qb, bq, N_TOK, Dm, Dm, Em * Dm, Dm, Dm,
      0L, 0L, 0L, 0L, eid, Dm);
  // ---- attention over experts ----
  attn_kernel<<<N_TOK / 4, 256, 0, stream>>>(qb, kv, ctxb, eid);
  // ---- out projection -> d_out (fp32) ----
  gemm_bt<false, false><<<dim3(N_TOK / 128, Dm / 128, 1), 256, 0, stream>>>(
      ctxb, ow, (float*)d_out, bo, N_TOK, Dm, Dm, Dm, Dm, Dm,
      0L, 0L, 0L, 0L, nullptr, 0);
}